// Round 15
// baseline (219.198 us; speedup 1.0000x reference)
//
#include <hip/hip_runtime.h>
#include <hip/hip_bf16.h>

#define DEVI __device__ __forceinline__
using u16 = unsigned short;
using u32 = unsigned int;

typedef __attribute__((ext_vector_type(4))) float f32x4;
typedef __attribute__((ext_vector_type(8))) __bf16 bf16x8;

constexpr int L_ = 2048;   // sequence length
// B=4, D=256, H=8, DH=32, DE=1024, M = B*L = 8192

DEVI u16 f2bf(float f){
  u32 u = __builtin_bit_cast(u32, f);
  u32 r = u + 0x7FFFu + ((u >> 16) & 1u);   // RNE
  return (u16)(r >> 16);
}
DEVI float sigm(float x){ return 1.f / (1.f + __expf(-x)); }

DEVI f32x4 mfma16(bf16x8 a, bf16x8 b, f32x4 c){
  return __builtin_amdgcn_mfma_f32_16x16x32_bf16(a, b, c, 0, 0, 0);
}

DEVI void gload16(const u16* src, u16* lds){
  __builtin_amdgcn_global_load_lds(
      (const __attribute__((address_space(1))) u32*)src,
      (__attribute__((address_space(3))) u32*)lds, 16, 0, 0);
}

#define WAITV(N) asm volatile("s_waitcnt vmcnt(" #N ")" ::: "memory")

// ---------- prep_all: 6x weight transpose + tmlp1 + cvt ctx->bf16 + LN0+SiLU ----------
// blocks: [0,1728) wtrans | [1728,1732) tmlp1 | [1732,3780) cvt | [3780,5828) ln0
__global__ __launch_bounds__(256)
void prep_all(const float* __restrict__ Wq,   u16* __restrict__ wtq,
              const float* __restrict__ Wkv1, u16* __restrict__ wtkv1,
              const float* __restrict__ Wkv2, u16* __restrict__ wtkv2,
              const float* __restrict__ Wm,   u16* __restrict__ wtm,
              const float* __restrict__ Wff1, u16* __restrict__ wtff1,
              const float* __restrict__ Wff2, u16* __restrict__ wtff2,
              const float* __restrict__ tvec, const float* __restrict__ Wt1,
              const float* __restrict__ bt1,  float* __restrict__ ub,
              const float* __restrict__ ctx,  u16* __restrict__ ctx_bf,
              const float* __restrict__ x,    const float* __restrict__ pos,
              const float* __restrict__ ln_g, const float* __restrict__ ln_b,
              u16* __restrict__ qin_bf){
  __shared__ float smem[32 * 33];
  const int id = blockIdx.x;
  if (id >= 3780){
    // ln_silu MODE 0: silu(LN(x)+pos)
    const int row  = (id - 3780) * 4 + (threadIdx.x >> 6);
    const int lane = threadIdx.x & 63;
    const long base = (long)row * 256 + lane * 4;
    float4 x4 = *(const float4*)(x + base);
    float v[4] = {x4.x, x4.y, x4.z, x4.w};
    float s = v[0] + v[1] + v[2] + v[3];
    #pragma unroll
    for (int d = 1; d < 64; d <<= 1) s += __shfl_xor(s, d);
    const float mean = s * (1.f / 256.f);
    float q = 0.f;
    #pragma unroll
    for (int i = 0; i < 4; ++i){ float dd = v[i] - mean; q += dd * dd; }
    #pragma unroll
    for (int d = 1; d < 64; d <<= 1) q += __shfl_xor(q, d);
    const float rstd = rsqrtf(q * (1.f / 256.f) + 1e-5f);
    float4 g4 = *(const float4*)(ln_g + lane * 4);
    float4 b4 = *(const float4*)(ln_b + lane * 4);
    float4 pp = *(const float4*)(pos + (long)(row & (L_ - 1)) * 256 + lane * 4);
    float gv[4] = {g4.x, g4.y, g4.z, g4.w}, bb[4] = {b4.x, b4.y, b4.z, b4.w};
    float pe[4] = {pp.x, pp.y, pp.z, pp.w};
    ushort4 o; u16 tmp[4];
    #pragma unroll
    for (int i = 0; i < 4; ++i){
      float y = (v[i] - mean) * rstd * gv[i] + bb[i] + pe[i];
      y = y * sigm(y);
      tmp[i] = f2bf(y);
    }
    o.x = tmp[0]; o.y = tmp[1]; o.z = tmp[2]; o.w = tmp[3];
    *(ushort4*)(qin_bf + base) = o;
    return;
  }
  if (id >= 1732){                    // cvt_bf
    long i = ((long)(id - 1732) * 256 + threadIdx.x) * 4;
    float4 v = *(const float4*)(ctx + i);
    ushort4 o; o.x = f2bf(v.x); o.y = f2bf(v.y); o.z = f2bf(v.z); o.w = f2bf(v.w);
    *(ushort4*)(ctx_bf + i) = o;
    return;
  }
  if (id >= 1728){                    // tmlp1: u = silu(t @ Wt1 + bt1)
    int b = id - 1728, j = threadIdx.x;
    smem[j] = tvec[b * 256 + j];
    __syncthreads();
    float acc = bt1[j];
    for (int k = 0; k < 256; ++k) acc += smem[k] * Wt1[k * 256 + j];
    ub[b * 256 + j] = acc * sigm(acc);
    return;
  }
  const float* W; u16* WT; int K, N, local, nx;
  if      (id <   64){ W = Wq;   WT = wtq;   K = 256;  N = 256;  local = id;        nx = 8;  }
  else if (id <  128){ W = Wkv1; WT = wtkv1; K = 256;  N = 256;  local = id - 64;   nx = 8;  }
  else if (id <  704){ W = Wkv2; WT = wtkv2; K = 256;  N = 2304; local = id - 128;  nx = 72; }
  else if (id < 1216){ W = Wm;   WT = wtm;   K = 2048; N = 256;  local = id - 704;  nx = 8;  }
  else if (id < 1472){ W = Wff1; WT = wtff1; K = 256;  N = 1024; local = id - 1216; nx = 32; }
  else               { W = Wff2; WT = wtff2; K = 1024; N = 256;  local = id - 1472; nx = 8;  }
  int n0 = (local % nx) * 32, k0 = (local / nx) * 32;
  float (*tile)[33] = (float(*)[33])smem;
  int tx = threadIdx.x & 31, ty = threadIdx.x >> 5;
  #pragma unroll
  for (int i = 0; i < 4; ++i){ int kk = ty + i*8; tile[kk][tx] = W[(long)(k0+kk)*N + n0 + tx]; }
  __syncthreads();
  #pragma unroll
  for (int i = 0; i < 4; ++i){ int nn = ty + i*8; WT[(long)(n0+nn)*K + k0 + tx] = f2bf(tile[tx][nn]); }
}

// ---------- fused LayerNorm(+add)+SiLU -> bf16 (MODE 1: plain, MODE 2: +t_shift) ----------
template<int MODE>
__global__ __launch_bounds__(256)
void ln_silu(const float* __restrict__ in, const float* __restrict__ add,
             const float* __restrict__ g, const float* __restrict__ bvec,
             u16* __restrict__ out){
  const int row  = blockIdx.x * 4 + (threadIdx.x >> 6);
  const int lane = threadIdx.x & 63;
  const long base = (long)row * 256 + lane * 4;
  float4 x4 = *(const float4*)(in + base);
  float v[4] = {x4.x, x4.y, x4.z, x4.w};
  if constexpr (MODE == 2){
    float4 s4 = *(const float4*)(add + (row >> 11) * 1280 + lane * 4); // t_shift
    v[0] += s4.x; v[1] += s4.y; v[2] += s4.z; v[3] += s4.w;
  }
  float s = v[0] + v[1] + v[2] + v[3];
  #pragma unroll
  for (int d = 1; d < 64; d <<= 1) s += __shfl_xor(s, d);
  const float mean = s * (1.f / 256.f);
  float q = 0.f;
  #pragma unroll
  for (int i = 0; i < 4; ++i){ float dd = v[i] - mean; q += dd * dd; }
  #pragma unroll
  for (int d = 1; d < 64; d <<= 1) q += __shfl_xor(q, d);
  const float rstd = rsqrtf(q * (1.f / 256.f) + 1e-5f);
  float4 g4 = *(const float4*)(g + lane * 4);
  float4 b4 = *(const float4*)(bvec + lane * 4);
  float gv[4] = {g4.x, g4.y, g4.z, g4.w}, bb[4] = {b4.x, b4.y, b4.z, b4.w};
  ushort4 o; u16 tmp[4];
  #pragma unroll
  for (int i = 0; i < 4; ++i){
    float y = (v[i] - mean) * rstd * gv[i] + bb[i];
    y = y * sigm(y);
    tmp[i] = f2bf(y);
  }
  o.x = tmp[0]; o.y = tmp[1]; o.z = tmp[2]; o.w = tmp[3];
  *(ushort4*)(out + base) = o;
}

// ---------- shared GEMM body: 64x128 tile, 512 thr, 3-buffer, counted vmcnt(3) ----------
// EPI 0: bf16  1: f32  2: f32+res  3: kv-split + FUSED V-transpose  4: FF1 gate  5: *qk-scale
template<int EPI>
DEVI void gemm_body(const u16* __restrict__ A, const u16* __restrict__ BT,
                    const float* __restrict__ bias, const float* __restrict__ res,
                    const float* __restrict__ thv,
                    float* __restrict__ outF, u16* __restrict__ outB, u16* __restrict__ outB2,
                    int N, int K, u16* smem, int by){
  u16* As = smem;
  u16* Bs = smem + 3 * 4096;
  const int t = threadIdx.x, lane = t & 63;
  const int lr = lane & 15, lg = lane >> 4;
  const int wv = t >> 6;
  const int wrow = (wv >> 2) * 32;
  const int wcol = (wv & 3) * 32;
  const long bm = (long)blockIdx.x * 64, bn = (long)by * 128;

  auto stage = [&](int step, int buf){
    const int kt = step * 64;
    {
      int o = t * 16;
      int row = o >> 7, cb = o & 127;
      int scb = cb ^ ((row & 7) << 4);
      gload16(&A[(bm + row) * K + kt + (scb >> 1)], &As[buf * 4096 + (o >> 1)]);
    }
    #pragma unroll
    for (int i = 0; i < 2; ++i){
      int o = t * 16 + i * 8192;
      int row = o >> 7, cb = o & 127;
      int scb = cb ^ ((row & 7) << 4);
      gload16(&BT[(bn + row) * K + kt + (scb >> 1)], &Bs[buf * 8192 + (o >> 1)]);
    }
  };

  const f32x4 zero = {0.f, 0.f, 0.f, 0.f};
  f32x4 acc[2][2];
  acc[0][0] = zero; acc[0][1] = zero; acc[1][0] = zero; acc[1][1] = zero;

  const int ns = K >> 6;
  stage(0, 0); stage(1, 1);
  int bufc = 0;
  for (int i = 0; i < ns; ++i){
    if (i + 1 < ns) WAITV(3); else WAITV(0);
    __builtin_amdgcn_s_barrier();
    __builtin_amdgcn_sched_barrier(0);
    if (i + 2 < ns){
      int nb = bufc + 2; if (nb >= 3) nb -= 3;
      stage(i + 2, nb);
    }
    __builtin_amdgcn_s_setprio(1);
    #pragma unroll
    for (int ks = 0; ks < 2; ++ks){
      bf16x8 av[2], bv[2];
      const int cb = (ks * 32 + lg * 8) * 2;
      #pragma unroll
      for (int m = 0; m < 2; ++m){
        int row = wrow + m * 16 + lr;
        av[m] = *(const bf16x8*)((const char*)&As[bufc * 4096] + row * 128 + (cb ^ ((row & 7) << 4)));
      }
      #pragma unroll
      for (int n = 0; n < 2; ++n){
        int row = wcol + n * 16 + lr;
        bv[n] = *(const bf16x8*)((const char*)&Bs[bufc * 8192] + row * 128 + (cb ^ ((row & 7) << 4)));
      }
      #pragma unroll
      for (int m = 0; m < 2; ++m)
        #pragma unroll
        for (int n = 0; n < 2; ++n)
          acc[m][n] = mfma16(av[m], bv[n], acc[m][n]);
    }
    __builtin_amdgcn_s_setprio(0);
    bufc = (bufc + 1 == 3) ? 0 : bufc + 1;
  }

  constexpr float QSC = 0.17677669529663687f * 1.4426950408889634f; // 1/sqrt(32)*log2e

  if constexpr (EPI == 3){
    if (by >= 2){
      // V columns: transpose 64x128 tile via LDS, write VT[bh][d][m] coalesced
      __syncthreads();                       // done reading As/Bs
      u16* tile = smem;                      // [128 col][72 pad] = 18KB
      #pragma unroll
      for (int m = 0; m < 2; ++m)
        #pragma unroll
        for (int n = 0; n < 2; ++n){
          int c_l = wcol + n * 16 + lr;
          long col = bn + c_l;
          int rbase = wrow + m * 16 + lg * 4;
          ushort4 pk;
          u16* pp = (u16*)&pk;
          #pragma unroll
          for (int r = 0; r < 4; ++r)
            pp[r] = f2bf(acc[m][n][r] + bias[col]);
          *(ushort4*)&tile[c_l * 72 + rbase] = pk;
        }
      __syncthreads();
      const int b = (int)(bm >> 11), l0 = (int)(bm & 2047);
      const int hdb = (int)bn - 256;
      const int h = hdb >> 8, d0 = hdb & 255;
      const int dd = t >> 2, lh = (t & 3) * 16;
      u16* dst = outB2 + ((long)((b * 8 + h) * 256 + d0 + dd)) * 2048 + l0 + lh;
      *(uint4*)(dst + 0) = *(const uint4*)&tile[dd * 72 + lh + 0];
      *(uint4*)(dst + 8) = *(const uint4*)&tile[dd * 72 + lh + 8];
      return;
    }
    // K columns (by < 2): plain bf16 write
    #pragma unroll
    for (int m = 0; m < 2; ++m)
      #pragma unroll
      for (int n = 0; n < 2; ++n)
        #pragma unroll
        for (int r = 0; r < 4; ++r){
          long row = bm + wrow + m * 16 + lg * 4 + r;
          long col = bn + wcol + n * 16 + lr;
          outB[row * 256 + col] = f2bf(acc[m][n][r] + bias[col]);
        }
    return;
  }

  #pragma unroll
  for (int m = 0; m < 2; ++m)
    #pragma unroll
    for (int n = 0; n < 2; ++n)
      #pragma unroll
      for (int r = 0; r < 4; ++r){
        long row = bm + wrow + m * 16 + lg * 4 + r;
        long col = bn + wcol + n * 16 + lr;
        float v = acc[m][n][r] + bias[col];
        if constexpr (EPI == 0){
          outB[row * N + col] = f2bf(v);
        } else if constexpr (EPI == 1){
          outF[row * N + col] = v;
        } else if constexpr (EPI == 2){
          outF[row * N + col] = v + res[row * N + col];
        } else if constexpr (EPI == 4){
          int b = (int)(row >> 11);
          float ts = thv[b * 1280 + 256 + (int)col];
          float z = v * sigm(ts);
          outB[row * N + col] = f2bf(z * sigm(z));
        } else {
          outB[row * N + col] = f2bf(v * QSC);
        }
      }
}

template<int EPI>
__global__ __launch_bounds__(512, 4)
void gemm2(const u16* __restrict__ A, const u16* __restrict__ BT,
           const float* __restrict__ bias, const float* __restrict__ res,
           const float* __restrict__ thv,
           float* __restrict__ outF, u16* __restrict__ outB, u16* __restrict__ outB2,
           int M, int N, int K){
  __shared__ u16 smem[3 * 4096 + 3 * 8192];   // 72KB
  gemm_body<EPI>(A, BT, bias, res, thv, outF, outB, outB2, N, K, smem, blockIdx.y);
}

// dual: q-proj + kv1 + tmlp2 in one full-machine launch (grid 128x5)
template<int E0, int E1>
__global__ __launch_bounds__(512, 4)
void gemm2_dual(const u16* __restrict__ A0, const u16* __restrict__ B0,
                const float* __restrict__ bias0, u16* __restrict__ out0,
                const u16* __restrict__ A1, const u16* __restrict__ B1,
                const float* __restrict__ bias1, float* __restrict__ out1,
                const float* __restrict__ ub, const float* __restrict__ Wt2,
                const float* __restrict__ bt2, float* __restrict__ th,
                int N, int K){
  __shared__ u16 smem[3 * 4096 + 3 * 8192];   // 72KB
  if (blockIdx.y == 4){
    if (blockIdx.x >= 20) return;
    // tmlp2: th = silu(u) @ Wt2 + bt2   (20 logical blocks; all 512 threads via t&255)
    float* us = (float*)smem;
    int local = blockIdx.x, b = local & 3, jb = local >> 2;
    int tj = threadIdx.x & 255;
    us[tj] = ub[b * 256 + tj];
    __syncthreads();
    int j = jb * 256 + tj;
    float acc = bt2[j];
    for (int k = 0; k < 256; ++k) acc += us[k] * Wt2[k * 1280 + j];
    th[b * 1280 + j] = acc;
    return;
  }
  if (blockIdx.y < 2)
    gemm_body<E0>(A0, B0, bias0, nullptr, nullptr, nullptr, out0, nullptr, N, K, smem, blockIdx.y);
  else
    gemm_body<E1>(A1, B1, bias1, nullptr, nullptr, out1, nullptr, nullptr, N, K, smem, blockIdx.y - 2);
}

// ---------- gemm3: 32x128 tile, 256 thr, 4 waves (A rows broadcast), 60KB -> 2 blocks/CU ----
// full-machine grid (256, 2) for the N=256 GEMMs on the critical path. EPI 2 only.
__global__ __launch_bounds__(256, 2)
void gemm3(const u16* __restrict__ A, const u16* __restrict__ BT,
           const float* __restrict__ bias, const float* __restrict__ res,
           float* __restrict__ outF, int M, int N, int K){
  __shared__ u16 smem[3 * 2048 + 3 * 8192];   // 60KB
  u16* As = smem;
  u16* Bs = smem + 3 * 2048;
  const int t = threadIdx.x, lane = t & 63;
  const int lr = lane & 15, lg = lane >> 4;
  const int wcol = (t >> 6) * 32;
  const long bm = (long)blockIdx.x * 32, bn = (long)blockIdx.y * 128;

  auto stage = [&](int step, int buf){
    const int kt = step * 64;
    {
      int o = t * 16;                      // 4KB A tile
      int row = o >> 7, cb = o & 127;
      int scb = cb ^ ((row & 7) << 4);
      gload16(&A[(bm + row) * K + kt + (scb >> 1)], &As[buf * 2048 + (o >> 1)]);
    }
    #pragma unroll
    for (int i = 0; i < 4; ++i){           // 16KB B tile
      int o = t * 16 + i * 4096;
      int row = o >> 7, cb = o & 127;
      int scb = cb ^ ((row & 7) << 4);
      gload16(&BT[(bn + row) * K + kt + (scb >> 1)], &Bs[buf * 8192 + (o >> 1)]);
    }
  };

  const f32x4 zero = {0.f, 0.f, 0.f, 0.f};
  f32x4 acc[2][2];
  acc[0][0] = zero; acc[0][1] = zero; acc[1][0] = zero; acc[1][1] = zero;

  const int ns = K >> 6;
  stage(0, 0); stage(1, 1);
  int bufc = 0;
  for (int i = 0; i < ns; ++i){
    if (i + 1 < ns) WAITV(5); else WAITV(0);
    __builtin_amdgcn_s_barrier();
    __builtin_amdgcn_sched_barrier(0);
    if (i + 2 < ns){
      int nb = bufc + 2; if (nb >= 3) nb -= 3;
      stage(i + 2, nb);
    }
    __builtin_amdgcn_s_setprio(1);
    #pragma unroll
    for (int ks = 0; ks < 2; ++ks){
      bf16x8 av[2], bv[2];
      const int cb = (ks * 32 + lg * 8) * 2;
      #pragma unroll
      for (int m = 0; m < 2; ++m){
        int row = m * 16 + lr;             // all 4 waves read same A rows (LDS broadcast)
        av[m] = *(const bf16x8*)((const char*)&As[bufc * 2048] + row * 128 + (cb ^ ((row & 7) << 4)));
      }
      #pragma unroll
      for (int n = 0; n < 2; ++n){
        int row = wcol + n * 16 + lr;
        bv[n] = *(const bf16x8*)((const char*)&Bs[bufc * 8192] + row * 128 + (cb ^ ((row & 7) << 4)));
      }
      #pragma unroll
      for (int m = 0; m < 2; ++m)
        #pragma unroll
        for (int n = 0; n < 2; ++n)
          acc[m][n] = mfma16(av[m], bv[n], acc[m][n]);
    }
    __builtin_amdgcn_s_setprio(0);
    bufc = (bufc + 1 == 3) ? 0 : bufc + 1;
  }

  #pragma unroll
  for (int m = 0; m < 2; ++m)
    #pragma unroll
    for (int n = 0; n < 2; ++n)
      #pragma unroll
      for (int r = 0; r < 4; ++r){
        long row = bm + m * 16 + lg * 4 + r;
        long col = bn + wcol + n * 16 + lr;
        float v = acc[m][n][r] + bias[col];
        outF[row * N + col] = v + res[row * N + col];
      }
}

// ---------- flash attention v11: 4 waves x 32 q = 128 q/block, 512 blocks = 2/CU ----------
// One chunk per block (mirror-paired yc). LDS exactly 80KB (V dbuf 64KB + P 16KB).
// K prefetched to REGISTERS 1 tile ahead (L2 direct); V staged 1-ahead, WAITV(4).
// Per-q LDS reads halved vs attn7 (vf shared across 2 q-halves); softmax once per q.
__global__ __launch_bounds__(256, 2)
void attn11(const u16* __restrict__ Q, const u16* __restrict__ Kb,
            const u16* __restrict__ VT, u16* __restrict__ attout){
  const int bh = blockIdx.x, b = bh >> 3, h = bh & 7;
  const int yc = blockIdx.y;                   // 0..15, mirror-paired
  const int chunk = (yc < 8) ? yc : 23 - yc;
  const int n0 = chunk * 128;
  const int t = threadIdx.x;
  const int w = t >> 6, lane = t & 63, lr = lane & 15, lg = lane >> 4;
  const int n_lo = n0 + w * 32;                // this wave's 32 queries
  const int nt = (L_ - n0) >> 6;               // 32 - 2*chunk (>= 2)

  __shared__ u16 Vs[2][256 * 64];   // [d][m] 128B rows, XOR (d&7)<<4 byte swizzle (64KB)
  __shared__ u16 Ps[4][32 * 64];    // per-wave P [q][m], XOR (q&7)<<3 elem swizzle(16KB)
  u16* myP = &Ps[w][0];

  const f32x4 zero = {0.f, 0.f, 0.f, 0.f};
  const u16* vbase = VT + (long)bh * 256 * 2048;
  const u16* kbase = Kb + (long)(b * L_) * 256 + h * 32;

  auto stageV = [&](int m0, int buf){
    #pragma unroll
    for (int i = 0; i < 8; ++i){             // 256 thr x 16B x 8 = 32KB
      int ob = t * 16 + i * 4096;
      int d = ob >> 7, cb = ob & 127;
      int scb = cb ^ ((d & 7) << 4);
      gload16(vbase + (long)d * 2048 + m0 + (scb >> 1), &Vs[buf][ob >> 1]);
    }
  };

  bf16x8 qf[2];
  #pragma unroll
  for (int qh = 0; qh < 2; ++qh)
    qf[qh] = *(const bf16x8*)(Q + ((long)(b * L_ + n_lo + qh * 16 + lr)) * 256 + h * 32 + lg * 8);

  f32x4 o[2][16];
  #pragma unroll
  for (int qh = 0; qh < 2; ++qh)
    #pragma unroll
    for (int c2 = 0; c2 < 16; ++c2) o[qh][c2] = zero;
  float mrun[2] = {-1e30f, -1e30f}, srun[2] = {0.f, 0.f};

  // prologue: V tile 0 -> LDS, K tile 0 -> registers
  stageV(n0, 0);
  bf16x8 kf[4];
  #pragma unroll
  for (int c = 0; c < 4; ++c)
    kf[c] = *(const bf16x8*)(kbase + (long)(n0 + c * 16 + lr) * 256 + lg * 8);

  for (int tt = 0; tt < nt; ++tt){
    const int m0 = n0 + tt * 64;
    const int cur = tt & 1;
    if (tt + 1 < nt) WAITV(4); else WAITV(0);  // stageV(tt) done (newest 4 = kf loads)
    __builtin_amdgcn_s_barrier();
    __builtin_amdgcn_sched_barrier(0);
    bf16x8 kfN[4];
    if (tt + 1 < nt){
      stageV(m0 + 64, cur ^ 1);                // buf freed: all waves past tile tt-1
      #pragma unroll
      for (int c = 0; c < 4; ++c)
        kfN[c] = *(const bf16x8*)(kbase + (long)(m0 + 64 + c * 16 + lr) * 256 + lg * 8);
    }

    if (m0 + 64 > n_lo){
      const bool partial = (m0 < n_lo + 32);

      // swapped: S[m][q]; lane holds q = n_lo+qh*16+lr, m = m0+c*16+lg*4+r
      f32x4 sc[2][4];
      #pragma unroll
      for (int qh = 0; qh < 2; ++qh)
        #pragma unroll
        for (int c = 0; c < 4; ++c)
          sc[qh][c] = mfma16(kf[c], qf[qh], zero);

      if (partial){
        #pragma unroll
        for (int qh = 0; qh < 2; ++qh)
          #pragma unroll
          for (int c = 0; c < 4; ++c)
            #pragma unroll
            for (int r = 0; r < 4; ++r)
              if ((m0 + c * 16 + lg * 4 + r) < (n_lo + qh * 16 + lr)) sc[qh][c][r] = -1e30f;
      }

      float tmax[2]; bool needl = false;
      #pragma unroll
      for (int qh = 0; qh < 2; ++qh){
        float t0 = fmaxf(fmaxf(sc[qh][0][0], sc[qh][0][1]), fmaxf(sc[qh][0][2], sc[qh][0][3]));
        #pragma unroll
        for (int c = 1; c < 4; ++c)
          t0 = fmaxf(t0, fmaxf(fmaxf(sc[qh][c][0], sc[qh][c][1]),
                               fmaxf(sc[qh][c][2], sc[qh][c][3])));
        t0 = fmaxf(t0, __shfl_xor(t0, 16));
        t0 = fmaxf(t0, __shfl_xor(t0, 32));
        tmax[qh] = t0;
        needl |= (t0 > mrun[qh] + 11.5f);
      }
      if (__any(needl)){
        #pragma unroll
        for (int qh = 0; qh < 2; ++qh){
          float mn  = fmaxf(mrun[qh], tmax[qh]);
          float frc = exp2f(mrun[qh] - mn);
          mrun[qh] = mn; srun[qh] *= frc;
          float f0 = __shfl(frc, lg * 4 + 0), f1 = __shfl(frc, lg * 4 + 1);
          float f2 = __shfl(frc, lg * 4 + 2), f3 = __shfl(frc, lg * 4 + 3);
          f32x4 fv = {f0, f1, f2, f3};
          #pragma unroll
          for (int c2 = 0; c2 < 16; ++c2) o[qh][c2] *= fv;
        }
      }

      // exp2 + row sum + P -> LDS (per-wave region, no barrier)
      #pragma unroll
      for (int qh = 0; qh < 2; ++qh){
        const int q = qh * 16 + lr;
        const int sw = (q & 7) << 3;
        float rs = 0.f;
        #pragma unroll
        for (int c = 0; c < 4; ++c){
          float e0 = exp2f(sc[qh][c][0] - mrun[qh]);
          float e1 = exp2f(sc[qh][c][1] - mrun[qh]);
          float e2 = exp2f(sc[qh][c][2] - mrun[qh]);
          float e3 = exp2f(sc[qh][c][3] - mrun[qh]);
          if (partial && mrun[qh] < -1e29f){ e0 = e1 = e2 = e3 = 0.f; }
          rs += (e0 + e1) + (e2 + e3);
          ushort4 pk;
          pk.x = __builtin_bit_cast(u16, (__bf16)e0);
          pk.y = __builtin_bit_cast(u16, (__bf16)e1);
          pk.z = __builtin_bit_cast(u16, (__bf16)e2);
          pk.w = __builtin_bit_cast(u16, (__bf16)e3);
          *(ushort4*)&myP[q * 64 + ((c * 16 + lg * 4) ^ sw)] = pk;
        }
        rs += __shfl_xor(rs, 16);
        rs += __shfl_xor(rs, 32);
        srun[qh] += rs;
      }

      // ---- PV (vf shared across both q-halves) ----
      __builtin_amdgcn_s_setprio(1);
      #pragma unroll
      for (int ks = 0; ks < 2; ++ks){
        bf16x8 pa[2];
        #pragma unroll
        for (int qh = 0; qh < 2; ++qh){
          const int q = qh * 16 + lr;
          pa[qh] = *(const bf16x8*)&myP[q * 64 + ((ks * 32 + lg * 8) ^ ((q & 7) << 3))];
        }
        #pragma unroll
        for (int c2 = 0; c2 < 16; ++c2){
          const int d = c2 * 16 + lr;
          bf16x8 vf = *(const bf16x8*)((const char*)&Vs[cur][0] + d * 128 +
                                       ((ks * 64 + lg * 16) ^ ((d & 7) << 4)));
          #pragma unroll
          for (int qh = 0; qh < 2; ++qh)
            o[qh][c2] = mfma16(pa[qh], vf, o[qh][c2]);
        }
      }
      __builtin_amdgcn_s_setprio(0);
    }
    if (tt + 1 < nt){
      #pragma unroll
      for (int c = 0; c < 4; ++c) kf[c] = kfN[c];
    }
  }

  // epilogue (srun/mrun live at lane q: redistribute via shfl)
  #pragma unroll
  for (int qh = 0; qh < 2; ++qh){
    float invc = 1.f / srun[qh];
    #pragma unroll
    for (int r = 0; r < 4; ++r){
      float inv = __shfl(invc, lg * 4 + r);
      long row = (long)(b * L_ + n_lo + qh * 16 + lg * 4 + r);
      #pragma unroll
      for (int c2 = 0; c2 < 16; ++c2)
        attout[row * 2048 + h * 256 + c2 * 16 + lr] = f2bf(o[qh][c2][r] * inv);
    }
  }
}

extern "C" void kernel_launch(void* const* d_in, const int* in_sizes, int n_in,
                              void* d_out, int out_size, void* d_ws, size_t ws_size,
                              hipStream_t stream){
  (void)in_sizes; (void)n_in; (void)out_size; (void)ws_size;
  const float* x    = (const float*)d_in[0];
  const float* ctx  = (const float*)d_in[1];
  const float* tin  = (const float*)d_in[2];
  const float* pos  = (const float*)d_in[3];
  const float* ln_g = (const float*)d_in[4];
  const float* ln_b = (const float*)d_in[5];
  const float* Wq   = (const float*)d_in[6];
  const float* bq   = (const float*)d_in[7];
  const float* Wkv1 = (const float*)d_in[8];
  const float* bkv1 = (const float*)d_in[9];
  const float* kvg  = (const float*)d_in[10];
  const float* kvb  = (const float*)d_in[11];
  const float* Wkv2 = (const float*)d_in[12];
  const float* bkv2 = (const float*)d_in[13];
  const float* Wm   = (const float*)d_in[14];
  const float* bm   = (const float*)d_in[15];
  const float* Wt1  = (const float*)d_in[16];
  const float* bt1  = (const float*)d_in[17];
  const float* Wt2  = (const float*)d_in[18];
  const float* bt2  = (const float*)d_in[19];
  const float* fg   = (const float*)d_in[20];
  const float* fb   = (const float*)d_in[21];
  const float* Wff1 = (const float*)d_in[22];
  const float* bff1 = (const float*)d_in[23];
  const float* Wff2 = (const float*)d_in[24];
  const float* bff2 = (const float*)d_in[25];

  char* ws = (char*)d_ws;
  u16*   wt_q   = (u16*)  (ws + 0);
  u16*   wt_kv1 = (u16*)  (ws + 131072);
  u16*   wt_kv2 = (u16*)  (ws + 262144);
  u16*   wt_m   = (u16*)  (ws + 1441792);
  u16*   wt_ff1 = (u16*)  (ws + 2490368);
  u16*   wt_ff2 = (u16*)  (ws + 3014656);
  u16*   ctx_bf = (u16*)  (ws + 3538944);    // later reused: ff1 input
  u16*   qin_bf = (u16*)  (ws + 7733248);    // later reused: kvln
  u16*   q_bf   = (u16*)  (ws + 11927552);
  float* kv1    = (float*)(ws + 16121856);   // later reused: x2
  u16*   k_bf   = (u16*)  (ws + 24510464);
  u16*   v_bf   = (u16*)  (ws + 28704768);   // attention out
  u16*   vT     = (u16*)  (ws + 62259200);   // later reused: gated h
  float* ub     = (float*)(ws + 95813632);
  float* th     = (float*)(ws + 95817728);

  // 1: weight prep + tmlp1 + ctx->bf16 + silu(LN(x)+pos)   (independent work overlapped)
  prep_all<<<5828, 256, 0, stream>>>(Wq, wt_q, Wkv1, wt_kv1, Wkv2, wt_kv2,
                                     Wm, wt_m, Wff1, wt_ff1, Wff2, wt_ff2,
                                     tin, Wt1, bt1, ub,
                                     ctx, ctx_bf, x, pos, ln_g, ln_b, qin_bf);
  // 2: q-proj (*scale) + kv1 + tmlp2 in ONE full-machine launch
  gemm2_dual<5,1><<<dim3(128, 5), 512, 0, stream>>>(qin_bf, wt_q, bq, q_bf,
                                                    ctx_bf, wt_kv1, bkv1, kv1,
                                                    ub, Wt2, bt2, th,
                                                    256, 256);
  // 3: silu(LN(kv1))
  ln_silu<1><<<2048, 256, 0, stream>>>(kv1, nullptr, kvg, kvb, qin_bf);
  // 4: kv = . @ Wkv2 + bkv2 -> K (bf16) + V transposed directly to VT[bh][d][m]
  gemm2<3><<<dim3(128, 18), 512, 0, stream>>>(qin_bf, wt_kv2, bkv2, nullptr, nullptr,
                                              nullptr, k_bf, vT, 8192, 2304, 256);
  // 5: attention (512 blocks, 2/CU, 32q/wave)
  attn11<<<dim3(32, 16), 256, 0, stream>>>(q_bf, k_bf, vT, v_bf);
  // 6: x2 = x + att @ Wm + bm  (full-machine gemm3)
  gemm3<<<dim3(256, 2), 256, 0, stream>>>(v_bf, wt_m, bm, x, kv1, 8192, 256, 2048);
  // 7: silu(LN(x2 + t_shift))
  ln_silu<2><<<2048, 256, 0, stream>>>(kv1, th, fg, fb, ctx_bf);
  // 8: h gated FF1 (writes into vT region, reused as gated h)
  gemm2<4><<<dim3(128, 8), 512, 0, stream>>>(ctx_bf, wt_ff1, bff1, nullptr, th,
                                             nullptr, (u16*)vT, nullptr, 8192, 1024, 256);
  // 9: out = h @ Wff2 + bff2 + x2  (full-machine gemm3)
  gemm3<<<dim3(256, 2), 256, 0, stream>>>((u16*)vT, wt_ff2, bff2, kv1,
                                          (float*)d_out, 8192, 256, 1024);
}

// Round 16
// 183.192 us; speedup vs baseline: 1.1965x; 1.1965x over previous
//
#include <hip/hip_runtime.h>
#include <hip/hip_bf16.h>

#define DEVI __device__ __forceinline__
using u16 = unsigned short;
using u32 = unsigned int;

typedef __attribute__((ext_vector_type(4))) float f32x4;
typedef __attribute__((ext_vector_type(8))) __bf16 bf16x8;

constexpr int L_ = 2048;   // sequence length
// B=4, D=256, H=8, DH=32, DE=1024, M = B*L = 8192

DEVI u16 f2bf(float f){
  u32 u = __builtin_bit_cast(u32, f);
  u32 r = u + 0x7FFFu + ((u >> 16) & 1u);   // RNE
  return (u16)(r >> 16);
}
DEVI float sigm(float x){ return 1.f / (1.f + __expf(-x)); }

DEVI f32x4 mfma16(bf16x8 a, bf16x8 b, f32x4 c){
  return __builtin_amdgcn_mfma_f32_16x16x32_bf16(a, b, c, 0, 0, 0);
}

DEVI void gload16(const u16* src, u16* lds){
  __builtin_amdgcn_global_load_lds(
      (const __attribute__((address_space(1))) u32*)src,
      (__attribute__((address_space(3))) u32*)lds, 16, 0, 0);
}
DEVI void gload4(const u16* src, u16* lds){
  __builtin_amdgcn_global_load_lds(
      (const __attribute__((address_space(1))) u32*)src,
      (__attribute__((address_space(3))) u32*)lds, 4, 0, 0);
}

#define WAITV(N) asm volatile("s_waitcnt vmcnt(" #N ")" ::: "memory")

// ---------- prep_all: 6x weight transpose + tmlp1 + cvt ctx->bf16 + LN0+SiLU ----------
// blocks: [0,1728) wtrans | [1728,1732) tmlp1 | [1732,3780) cvt | [3780,5828) ln0
__global__ __launch_bounds__(256)
void prep_all(const float* __restrict__ Wq,   u16* __restrict__ wtq,
              const float* __restrict__ Wkv1, u16* __restrict__ wtkv1,
              const float* __restrict__ Wkv2, u16* __restrict__ wtkv2,
              const float* __restrict__ Wm,   u16* __restrict__ wtm,
              const float* __restrict__ Wff1, u16* __restrict__ wtff1,
              const float* __restrict__ Wff2, u16* __restrict__ wtff2,
              const float* __restrict__ tvec, const float* __restrict__ Wt1,
              const float* __restrict__ bt1,  float* __restrict__ ub,
              const float* __restrict__ ctx,  u16* __restrict__ ctx_bf,
              const float* __restrict__ x,    const float* __restrict__ pos,
              const float* __restrict__ ln_g, const float* __restrict__ ln_b,
              u16* __restrict__ qin_bf){
  __shared__ float smem[32 * 33];
  const int id = blockIdx.x;
  if (id >= 3780){
    // ln_silu MODE 0: silu(LN(x)+pos)
    const int row  = (id - 3780) * 4 + (threadIdx.x >> 6);
    const int lane = threadIdx.x & 63;
    const long base = (long)row * 256 + lane * 4;
    float4 x4 = *(const float4*)(x + base);
    float v[4] = {x4.x, x4.y, x4.z, x4.w};
    float s = v[0] + v[1] + v[2] + v[3];
    #pragma unroll
    for (int d = 1; d < 64; d <<= 1) s += __shfl_xor(s, d);
    const float mean = s * (1.f / 256.f);
    float q = 0.f;
    #pragma unroll
    for (int i = 0; i < 4; ++i){ float dd = v[i] - mean; q += dd * dd; }
    #pragma unroll
    for (int d = 1; d < 64; d <<= 1) q += __shfl_xor(q, d);
    const float rstd = rsqrtf(q * (1.f / 256.f) + 1e-5f);
    float4 g4 = *(const float4*)(ln_g + lane * 4);
    float4 b4 = *(const float4*)(ln_b + lane * 4);
    float4 pp = *(const float4*)(pos + (long)(row & (L_ - 1)) * 256 + lane * 4);
    float gv[4] = {g4.x, g4.y, g4.z, g4.w}, bb[4] = {b4.x, b4.y, b4.z, b4.w};
    float pe[4] = {pp.x, pp.y, pp.z, pp.w};
    ushort4 o; u16 tmp[4];
    #pragma unroll
    for (int i = 0; i < 4; ++i){
      float y = (v[i] - mean) * rstd * gv[i] + bb[i] + pe[i];
      y = y * sigm(y);
      tmp[i] = f2bf(y);
    }
    o.x = tmp[0]; o.y = tmp[1]; o.z = tmp[2]; o.w = tmp[3];
    *(ushort4*)(qin_bf + base) = o;
    return;
  }
  if (id >= 1732){                    // cvt_bf
    long i = ((long)(id - 1732) * 256 + threadIdx.x) * 4;
    float4 v = *(const float4*)(ctx + i);
    ushort4 o; o.x = f2bf(v.x); o.y = f2bf(v.y); o.z = f2bf(v.z); o.w = f2bf(v.w);
    *(ushort4*)(ctx_bf + i) = o;
    return;
  }
  if (id >= 1728){                    // tmlp1: u = silu(t @ Wt1 + bt1)
    int b = id - 1728, j = threadIdx.x;
    smem[j] = tvec[b * 256 + j];
    __syncthreads();
    float acc = bt1[j];
    for (int k = 0; k < 256; ++k) acc += smem[k] * Wt1[k * 256 + j];
    ub[b * 256 + j] = acc * sigm(acc);
    return;
  }
  const float* W; u16* WT; int K, N, local, nx;
  if      (id <   64){ W = Wq;   WT = wtq;   K = 256;  N = 256;  local = id;        nx = 8;  }
  else if (id <  128){ W = Wkv1; WT = wtkv1; K = 256;  N = 256;  local = id - 64;   nx = 8;  }
  else if (id <  704){ W = Wkv2; WT = wtkv2; K = 256;  N = 2304; local = id - 128;  nx = 72; }
  else if (id < 1216){ W = Wm;   WT = wtm;   K = 2048; N = 256;  local = id - 704;  nx = 8;  }
  else if (id < 1472){ W = Wff1; WT = wtff1; K = 256;  N = 1024; local = id - 1216; nx = 32; }
  else               { W = Wff2; WT = wtff2; K = 1024; N = 256;  local = id - 1472; nx = 8;  }
  int n0 = (local % nx) * 32, k0 = (local / nx) * 32;
  float (*tile)[33] = (float(*)[33])smem;
  int tx = threadIdx.x & 31, ty = threadIdx.x >> 5;
  #pragma unroll
  for (int i = 0; i < 4; ++i){ int kk = ty + i*8; tile[kk][tx] = W[(long)(k0+kk)*N + n0 + tx]; }
  __syncthreads();
  #pragma unroll
  for (int i = 0; i < 4; ++i){ int nn = ty + i*8; WT[(long)(n0+nn)*K + k0 + tx] = f2bf(tile[tx][nn]); }
}

// ---------- fused LayerNorm(+add)+SiLU -> bf16 (MODE 1: plain, MODE 2: +t_shift) ----------
template<int MODE>
__global__ __launch_bounds__(256)
void ln_silu(const float* __restrict__ in, const float* __restrict__ add,
             const float* __restrict__ g, const float* __restrict__ bvec,
             u16* __restrict__ out){
  const int row  = blockIdx.x * 4 + (threadIdx.x >> 6);
  const int lane = threadIdx.x & 63;
  const long base = (long)row * 256 + lane * 4;
  float4 x4 = *(const float4*)(in + base);
  float v[4] = {x4.x, x4.y, x4.z, x4.w};
  if constexpr (MODE == 2){
    float4 s4 = *(const float4*)(add + (row >> 11) * 1280 + lane * 4); // t_shift
    v[0] += s4.x; v[1] += s4.y; v[2] += s4.z; v[3] += s4.w;
  }
  float s = v[0] + v[1] + v[2] + v[3];
  #pragma unroll
  for (int d = 1; d < 64; d <<= 1) s += __shfl_xor(s, d);
  const float mean = s * (1.f / 256.f);
  float q = 0.f;
  #pragma unroll
  for (int i = 0; i < 4; ++i){ float dd = v[i] - mean; q += dd * dd; }
  #pragma unroll
  for (int d = 1; d < 64; d <<= 1) q += __shfl_xor(q, d);
  const float rstd = rsqrtf(q * (1.f / 256.f) + 1e-5f);
  float4 g4 = *(const float4*)(g + lane * 4);
  float4 b4 = *(const float4*)(bvec + lane * 4);
  float gv[4] = {g4.x, g4.y, g4.z, g4.w}, bb[4] = {b4.x, b4.y, b4.z, b4.w};
  ushort4 o; u16 tmp[4];
  #pragma unroll
  for (int i = 0; i < 4; ++i){
    float y = (v[i] - mean) * rstd * gv[i] + bb[i];
    y = y * sigm(y);
    tmp[i] = f2bf(y);
  }
  o.x = tmp[0]; o.y = tmp[1]; o.z = tmp[2]; o.w = tmp[3];
  *(ushort4*)(out + base) = o;
}

// ---------- shared GEMM body: 64x128 tile, 512 thr, 3-buffer, counted vmcnt(3) ----------
// EPI 0: bf16  1: f32  2: f32+res  3: kv-split + FUSED V-transpose  4: FF1 gate  5: *qk-scale
template<int EPI>
DEVI void gemm_body(const u16* __restrict__ A, const u16* __restrict__ BT,
                    const float* __restrict__ bias, const float* __restrict__ res,
                    const float* __restrict__ thv,
                    float* __restrict__ outF, u16* __restrict__ outB, u16* __restrict__ outB2,
                    int N, int K, u16* smem, int by){
  u16* As = smem;
  u16* Bs = smem + 3 * 4096;
  const int t = threadIdx.x, lane = t & 63;
  const int lr = lane & 15, lg = lane >> 4;
  const int wv = t >> 6;
  const int wrow = (wv >> 2) * 32;
  const int wcol = (wv & 3) * 32;
  const long bm = (long)blockIdx.x * 64, bn = (long)by * 128;

  auto stage = [&](int step, int buf){
    const int kt = step * 64;
    {
      int o = t * 16;
      int row = o >> 7, cb = o & 127;
      int scb = cb ^ ((row & 7) << 4);
      gload16(&A[(bm + row) * K + kt + (scb >> 1)], &As[buf * 4096 + (o >> 1)]);
    }
    #pragma unroll
    for (int i = 0; i < 2; ++i){
      int o = t * 16 + i * 8192;
      int row = o >> 7, cb = o & 127;
      int scb = cb ^ ((row & 7) << 4);
      gload16(&BT[(bn + row) * K + kt + (scb >> 1)], &Bs[buf * 8192 + (o >> 1)]);
    }
  };

  const f32x4 zero = {0.f, 0.f, 0.f, 0.f};
  f32x4 acc[2][2];
  acc[0][0] = zero; acc[0][1] = zero; acc[1][0] = zero; acc[1][1] = zero;

  const int ns = K >> 6;
  stage(0, 0); stage(1, 1);
  int bufc = 0;
  for (int i = 0; i < ns; ++i){
    if (i + 1 < ns) WAITV(3); else WAITV(0);
    __builtin_amdgcn_s_barrier();
    __builtin_amdgcn_sched_barrier(0);
    if (i + 2 < ns){
      int nb = bufc + 2; if (nb >= 3) nb -= 3;
      stage(i + 2, nb);
    }
    __builtin_amdgcn_s_setprio(1);
    #pragma unroll
    for (int ks = 0; ks < 2; ++ks){
      bf16x8 av[2], bv[2];
      const int cb = (ks * 32 + lg * 8) * 2;
      #pragma unroll
      for (int m = 0; m < 2; ++m){
        int row = wrow + m * 16 + lr;
        av[m] = *(const bf16x8*)((const char*)&As[bufc * 4096] + row * 128 + (cb ^ ((row & 7) << 4)));
      }
      #pragma unroll
      for (int n = 0; n < 2; ++n){
        int row = wcol + n * 16 + lr;
        bv[n] = *(const bf16x8*)((const char*)&Bs[bufc * 8192] + row * 128 + (cb ^ ((row & 7) << 4)));
      }
      #pragma unroll
      for (int m = 0; m < 2; ++m)
        #pragma unroll
        for (int n = 0; n < 2; ++n)
          acc[m][n] = mfma16(av[m], bv[n], acc[m][n]);
    }
    __builtin_amdgcn_s_setprio(0);
    bufc = (bufc + 1 == 3) ? 0 : bufc + 1;
  }

  constexpr float QSC = 0.17677669529663687f * 1.4426950408889634f; // 1/sqrt(32)*log2e

  if constexpr (EPI == 3){
    if (by >= 2){
      // V columns: transpose 64x128 tile via LDS, write VT[bh][d][m] coalesced
      __syncthreads();                       // done reading As/Bs
      u16* tile = smem;                      // [128 col][72 pad] = 18KB
      #pragma unroll
      for (int m = 0; m < 2; ++m)
        #pragma unroll
        for (int n = 0; n < 2; ++n){
          int c_l = wcol + n * 16 + lr;
          long col = bn + c_l;
          int rbase = wrow + m * 16 + lg * 4;
          ushort4 pk;
          u16* pp = (u16*)&pk;
          #pragma unroll
          for (int r = 0; r < 4; ++r)
            pp[r] = f2bf(acc[m][n][r] + bias[col]);
          *(ushort4*)&tile[c_l * 72 + rbase] = pk;
        }
      __syncthreads();
      const int b = (int)(bm >> 11), l0 = (int)(bm & 2047);
      const int hdb = (int)bn - 256;
      const int h = hdb >> 8, d0 = hdb & 255;
      const int dd = t >> 2, lh = (t & 3) * 16;
      u16* dst = outB2 + ((long)((b * 8 + h) * 256 + d0 + dd)) * 2048 + l0 + lh;
      *(uint4*)(dst + 0) = *(const uint4*)&tile[dd * 72 + lh + 0];
      *(uint4*)(dst + 8) = *(const uint4*)&tile[dd * 72 + lh + 8];
      return;
    }
    // K columns (by < 2): plain bf16 write
    #pragma unroll
    for (int m = 0; m < 2; ++m)
      #pragma unroll
      for (int n = 0; n < 2; ++n)
        #pragma unroll
        for (int r = 0; r < 4; ++r){
          long row = bm + wrow + m * 16 + lg * 4 + r;
          long col = bn + wcol + n * 16 + lr;
          outB[row * 256 + col] = f2bf(acc[m][n][r] + bias[col]);
        }
    return;
  }

  #pragma unroll
  for (int m = 0; m < 2; ++m)
    #pragma unroll
    for (int n = 0; n < 2; ++n)
      #pragma unroll
      for (int r = 0; r < 4; ++r){
        long row = bm + wrow + m * 16 + lg * 4 + r;
        long col = bn + wcol + n * 16 + lr;
        float v = acc[m][n][r] + bias[col];
        if constexpr (EPI == 0){
          outB[row * N + col] = f2bf(v);
        } else if constexpr (EPI == 1){
          outF[row * N + col] = v;
        } else if constexpr (EPI == 2){
          outF[row * N + col] = v + res[row * N + col];
        } else if constexpr (EPI == 4){
          int b = (int)(row >> 11);
          float ts = thv[b * 1280 + 256 + (int)col];
          float z = v * sigm(ts);
          outB[row * N + col] = f2bf(z * sigm(z));
        } else {
          outB[row * N + col] = f2bf(v * QSC);
        }
      }
}

template<int EPI>
__global__ __launch_bounds__(512, 4)
void gemm2(const u16* __restrict__ A, const u16* __restrict__ BT,
           const float* __restrict__ bias, const float* __restrict__ res,
           const float* __restrict__ thv,
           float* __restrict__ outF, u16* __restrict__ outB, u16* __restrict__ outB2,
           int M, int N, int K){
  __shared__ u16 smem[3 * 4096 + 3 * 8192];   // 72KB
  gemm_body<EPI>(A, BT, bias, res, thv, outF, outB, outB2, N, K, smem, blockIdx.y);
}

// dual: q-proj + kv1 + tmlp2 in one full-machine launch (grid 128x5)
template<int E0, int E1>
__global__ __launch_bounds__(512, 4)
void gemm2_dual(const u16* __restrict__ A0, const u16* __restrict__ B0,
                const float* __restrict__ bias0, u16* __restrict__ out0,
                const u16* __restrict__ A1, const u16* __restrict__ B1,
                const float* __restrict__ bias1, float* __restrict__ out1,
                const float* __restrict__ ub, const float* __restrict__ Wt2,
                const float* __restrict__ bt2, float* __restrict__ th,
                int N, int K){
  __shared__ u16 smem[3 * 4096 + 3 * 8192];   // 72KB
  if (blockIdx.y == 4){
    if (blockIdx.x >= 20) return;
    // tmlp2: th = silu(u) @ Wt2 + bt2   (20 logical blocks; all 512 threads via t&255)
    float* us = (float*)smem;
    int local = blockIdx.x, b = local & 3, jb = local >> 2;
    int tj = threadIdx.x & 255;
    us[tj] = ub[b * 256 + tj];
    __syncthreads();
    int j = jb * 256 + tj;
    float acc = bt2[j];
    for (int k = 0; k < 256; ++k) acc += us[k] * Wt2[k * 1280 + j];
    th[b * 1280 + j] = acc;
    return;
  }
  if (blockIdx.y < 2)
    gemm_body<E0>(A0, B0, bias0, nullptr, nullptr, nullptr, out0, nullptr, N, K, smem, blockIdx.y);
  else
    gemm_body<E1>(A1, B1, bias1, nullptr, nullptr, out1, nullptr, nullptr, N, K, smem, blockIdx.y - 2);
}

// ---------- gemm3: 32x128 tile, 256 thr, 4 waves (A rows broadcast), 60KB -> 2 blocks/CU ----
// full-machine grid (256, 2) for the N=256 GEMMs on the critical path. EPI 2 only.
__global__ __launch_bounds__(256, 2)
void gemm3(const u16* __restrict__ A, const u16* __restrict__ BT,
           const float* __restrict__ bias, const float* __restrict__ res,
           float* __restrict__ outF, int M, int N, int K){
  __shared__ u16 smem[3 * 2048 + 3 * 8192];   // 60KB
  u16* As = smem;
  u16* Bs = smem + 3 * 2048;
  const int t = threadIdx.x, lane = t & 63;
  const int lr = lane & 15, lg = lane >> 4;
  const int wcol = (t >> 6) * 32;
  const long bm = (long)blockIdx.x * 32, bn = (long)blockIdx.y * 128;

  auto stage = [&](int step, int buf){
    const int kt = step * 64;
    {
      int o = t * 16;                      // 4KB A tile
      int row = o >> 7, cb = o & 127;
      int scb = cb ^ ((row & 7) << 4);
      gload16(&A[(bm + row) * K + kt + (scb >> 1)], &As[buf * 2048 + (o >> 1)]);
    }
    #pragma unroll
    for (int i = 0; i < 4; ++i){           // 16KB B tile
      int o = t * 16 + i * 4096;
      int row = o >> 7, cb = o & 127;
      int scb = cb ^ ((row & 7) << 4);
      gload16(&BT[(bn + row) * K + kt + (scb >> 1)], &Bs[buf * 8192 + (o >> 1)]);
    }
  };

  const f32x4 zero = {0.f, 0.f, 0.f, 0.f};
  f32x4 acc[2][2];
  acc[0][0] = zero; acc[0][1] = zero; acc[1][0] = zero; acc[1][1] = zero;

  const int ns = K >> 6;
  stage(0, 0); stage(1, 1);
  int bufc = 0;
  for (int i = 0; i < ns; ++i){
    if (i + 1 < ns) WAITV(5); else WAITV(0);
    __builtin_amdgcn_s_barrier();
    __builtin_amdgcn_sched_barrier(0);
    if (i + 2 < ns){
      int nb = bufc + 2; if (nb >= 3) nb -= 3;
      stage(i + 2, nb);
    }
    __builtin_amdgcn_s_setprio(1);
    #pragma unroll
    for (int ks = 0; ks < 2; ++ks){
      bf16x8 av[2], bv[2];
      const int cb = (ks * 32 + lg * 8) * 2;
      #pragma unroll
      for (int m = 0; m < 2; ++m){
        int row = m * 16 + lr;             // all 4 waves read same A rows (LDS broadcast)
        av[m] = *(const bf16x8*)((const char*)&As[bufc * 2048] + row * 128 + (cb ^ ((row & 7) << 4)));
      }
      #pragma unroll
      for (int n = 0; n < 2; ++n){
        int row = wcol + n * 16 + lr;
        bv[n] = *(const bf16x8*)((const char*)&Bs[bufc * 8192] + row * 128 + (cb ^ ((row & 7) << 4)));
      }
      #pragma unroll
      for (int m = 0; m < 2; ++m)
        #pragma unroll
        for (int n = 0; n < 2; ++n)
          acc[m][n] = mfma16(av[m], bv[n], acc[m][n]);
    }
    __builtin_amdgcn_s_setprio(0);
    bufc = (bufc + 1 == 3) ? 0 : bufc + 1;
  }

  #pragma unroll
  for (int m = 0; m < 2; ++m)
    #pragma unroll
    for (int n = 0; n < 2; ++n)
      #pragma unroll
      for (int r = 0; r < 4; ++r){
        long row = bm + m * 16 + lg * 4 + r;
        long col = bn + wcol + n * 16 + lr;
        float v = acc[m][n][r] + bias[col];
        outF[row * N + col] = v + res[row * N + col];
      }
}

// ---------- flash attention v7 (best measured: 86.7us): 8 waves x 16 q, seq halves ----------
__global__ __launch_bounds__(512, 2)
void attn7(const u16* __restrict__ Q, const u16* __restrict__ Kb,
           const u16* __restrict__ VT, u16* __restrict__ attout){
  const int bh = blockIdx.x, b = bh >> 3, h = bh & 7;
  const int p  = blockIdx.y;                 // 0..7
  const int t  = threadIdx.x;
  const int w  = t >> 6, lane = t & 63, lr = lane & 15, lg = lane >> 4;

  __shared__ u16 Vs[3][256 * 64];   // [d][m] 128B rows, XOR (d&7)<<4 byte swizzle (96KB)
  __shared__ u16 Ks[3][64 * 32];    // [m][dh] 64B rows, 8-elem-block XOR (m&3)    (12KB)
  __shared__ u16 Ps[8][16 * 64];    // per-wave P [q][m], XOR (q&7)<<3 elem swizzle(16KB)
  u16* myP = &Ps[w][0];

  const f32x4 zero = {0.f, 0.f, 0.f, 0.f};
  const u16* vbase = VT + (long)bh * 256 * 2048;
  const u16* kbase = Kb + (long)(b * L_) * 256 + h * 32;

  auto stage = [&](int m0, int buf){
    #pragma unroll
    for (int i = 0; i < 4; ++i){
      int ob = t * 16 + i * 8192;
      int d = ob >> 7, cb = ob & 127;
      int scb = cb ^ ((d & 7) << 4);
      gload16(vbase + (long)d * 2048 + m0 + (scb >> 1), &Vs[buf][ob >> 1]);
    }
    #pragma unroll
    for (int i = 0; i < 2; ++i){
      int g = t + i * 512;                 // 4B granule id, 1024 total
      int row = g >> 4, sl = g & 15;
      int scol = ((sl & 3) << 1) + ((((sl >> 2) ^ (row & 3))) << 3);
      gload4(kbase + (long)(m0 + row) * 256 + scol, &Ks[buf][g << 1]);
    }
  };

  for (int half = 0; half < 2; ++half){
    const int chunk = half ? (15 - p) : p;
    const int n0 = chunk * 128;
    const int n_lo = n0 + w * 16;            // this wave's 16 queries
    const int nt = (L_ - n0) >> 6;           // >= 2 always

    bf16x8 qf = *(const bf16x8*)(Q + ((long)(b * L_ + n_lo + lr)) * 256 + h * 32 + lg * 8);

    f32x4 o[16];
    #pragma unroll
    for (int c2 = 0; c2 < 16; ++c2) o[c2] = zero;
    float mrun = -1e30f, srun = 0.f;

    stage(n0, 0); stage(n0 + 64, 1);

    int bufc = 0;
    for (int tt = 0; tt < nt; ++tt){
      const int m0 = n0 + tt * 64;
      if (tt + 1 < nt) WAITV(6); else WAITV(0);   // tile tt's 6 ops complete
      __builtin_amdgcn_s_barrier();
      __builtin_amdgcn_sched_barrier(0);
      if (tt + 2 < nt){
        int nb = bufc + 2; if (nb >= 3) nb -= 3;
        stage(m0 + 128, nb);                      // buffer freed by tile tt-1
      }

      if (m0 + 64 > n_lo){
        const bool partial = (m0 < n_lo + 16);

        bf16x8 kf[4];
        #pragma unroll
        for (int c = 0; c < 4; ++c){
          int row = c * 16 + lr;
          kf[c] = *(const bf16x8*)&Ks[bufc][row * 32 + ((lg ^ (row & 3)) << 3)];
        }
        // swapped: S[m][q]; lane holds q = n_lo+lr, m = m0+c*16+lg*4+r
        f32x4 sc[4];
        #pragma unroll
        for (int c = 0; c < 4; ++c)
          sc[c] = mfma16(kf[c], qf, zero);

        if (partial){
          #pragma unroll
          for (int c = 0; c < 4; ++c)
            #pragma unroll
            for (int r = 0; r < 4; ++r)
              if ((m0 + c * 16 + lg * 4 + r) < (n_lo + lr)) sc[c][r] = -1e30f;
        }

        float t0 = fmaxf(fmaxf(sc[0][0], sc[0][1]), fmaxf(sc[0][2], sc[0][3]));
        #pragma unroll
        for (int c = 1; c < 4; ++c)
          t0 = fmaxf(t0, fmaxf(fmaxf(sc[c][0], sc[c][1]), fmaxf(sc[c][2], sc[c][3])));
        t0 = fmaxf(t0, __shfl_xor(t0, 16));
        t0 = fmaxf(t0, __shfl_xor(t0, 32));
        const bool needl = (t0 > mrun + 11.5f);
        if (__any(needl)){
          float mn  = fmaxf(mrun, t0);
          float frc = exp2f(mrun - mn);
          mrun = mn; srun *= frc;
          float f0 = __shfl(frc, lg * 4 + 0), f1 = __shfl(frc, lg * 4 + 1);
          float f2 = __shfl(frc, lg * 4 + 2), f3 = __shfl(frc, lg * 4 + 3);
          f32x4 fv = {f0, f1, f2, f3};
          #pragma unroll
          for (int c2 = 0; c2 < 16; ++c2) o[c2] *= fv;
        }

        // exp2 + row sum + P -> LDS (per-wave region, no barrier)
        {
          const int q = lr, sw = (q & 7) << 3;
          float rs = 0.f;
          #pragma unroll
          for (int c = 0; c < 4; ++c){
            float e0 = exp2f(sc[c][0] - mrun);
            float e1 = exp2f(sc[c][1] - mrun);
            float e2 = exp2f(sc[c][2] - mrun);
            float e3 = exp2f(sc[c][3] - mrun);
            if (partial && mrun < -1e29f){ e0 = e1 = e2 = e3 = 0.f; }
            rs += (e0 + e1) + (e2 + e3);
            ushort4 pk;
            pk.x = __builtin_bit_cast(u16, (__bf16)e0);
            pk.y = __builtin_bit_cast(u16, (__bf16)e1);
            pk.z = __builtin_bit_cast(u16, (__bf16)e2);
            pk.w = __builtin_bit_cast(u16, (__bf16)e3);
            *(ushort4*)&myP[q * 64 + ((c * 16 + lg * 4) ^ sw)] = pk;
          }
          rs += __shfl_xor(rs, 16);
          rs += __shfl_xor(rs, 32);
          srun += rs;
        }

        // ---- PV ----
        __builtin_amdgcn_s_setprio(1);
        #pragma unroll
        for (int ks = 0; ks < 2; ++ks){
          bf16x8 pa = *(const bf16x8*)&myP[lr * 64 + ((ks * 32 + lg * 8) ^ ((lr & 7) << 3))];
          #pragma unroll
          for (int c2 = 0; c2 < 16; ++c2){
            const int d = c2 * 16 + lr;
            bf16x8 vf = *(const bf16x8*)((const char*)&Vs[bufc][0] + d * 128 +
                                         ((ks * 64 + lg * 16) ^ ((d & 7) << 4)));
            o[c2] = mfma16(pa, vf, o[c2]);
          }
        }
        __builtin_amdgcn_s_setprio(0);
      }
      bufc = (bufc + 1 == 3) ? 0 : bufc + 1;
    }

    // epilogue (srun/mrun live at lane q=lr: redistribute via shfl)
    {
      float invc = 1.f / srun;
      #pragma unroll
      for (int r = 0; r < 4; ++r){
        float inv = __shfl(invc, lg * 4 + r);
        long row = (long)(b * L_ + n_lo + lg * 4 + r);
        #pragma unroll
        for (int c2 = 0; c2 < 16; ++c2)
          attout[row * 2048 + h * 256 + c2 * 16 + lr] = f2bf(o[c2][r] * inv);
      }
    }
    WAITV(0);          // drain epilogue stores so half-1's counted vmcnt is exact
    __syncthreads();   // buffers reused by next half
  }
}

extern "C" void kernel_launch(void* const* d_in, const int* in_sizes, int n_in,
                              void* d_out, int out_size, void* d_ws, size_t ws_size,
                              hipStream_t stream){
  (void)in_sizes; (void)n_in; (void)out_size; (void)ws_size;
  const float* x    = (const float*)d_in[0];
  const float* ctx  = (const float*)d_in[1];
  const float* tin  = (const float*)d_in[2];
  const float* pos  = (const float*)d_in[3];
  const float* ln_g = (const float*)d_in[4];
  const float* ln_b = (const float*)d_in[5];
  const float* Wq   = (const float*)d_in[6];
  const float* bq   = (const float*)d_in[7];
  const float* Wkv1 = (const float*)d_in[8];
  const float* bkv1 = (const float*)d_in[9];
  const float* kvg  = (const float*)d_in[10];
  const float* kvb  = (const float*)d_in[11];
  const float* Wkv2 = (const float*)d_in[12];
  const float* bkv2 = (const float*)d_in[13];
  const float* Wm   = (const float*)d_in[14];
  const float* bm   = (const float*)d_in[15];
  const float* Wt1  = (const float*)d_in[16];
  const float* bt1  = (const float*)d_in[17];
  const float* Wt2  = (const float*)d_in[18];
  const float* bt2  = (const float*)d_in[19];
  const float* fg   = (const float*)d_in[20];
  const float* fb   = (const float*)d_in[21];
  const float* Wff1 = (const float*)d_in[22];
  const float* bff1 = (const float*)d_in[23];
  const float* Wff2 = (const float*)d_in[24];
  const float* bff2 = (const float*)d_in[25];

  char* ws = (char*)d_ws;
  u16*   wt_q   = (u16*)  (ws + 0);
  u16*   wt_kv1 = (u16*)  (ws + 131072);
  u16*   wt_kv2 = (u16*)  (ws + 262144);
  u16*   wt_m   = (u16*)  (ws + 1441792);
  u16*   wt_ff1 = (u16*)  (ws + 2490368);
  u16*   wt_ff2 = (u16*)  (ws + 3014656);
  u16*   ctx_bf = (u16*)  (ws + 3538944);    // later reused: ff1 input
  u16*   qin_bf = (u16*)  (ws + 7733248);    // later reused: kvln
  u16*   q_bf   = (u16*)  (ws + 11927552);
  float* kv1    = (float*)(ws + 16121856);   // later reused: x2
  u16*   k_bf   = (u16*)  (ws + 24510464);
  u16*   v_bf   = (u16*)  (ws + 28704768);   // attention out
  u16*   vT     = (u16*)  (ws + 62259200);   // later reused: gated h
  float* ub     = (float*)(ws + 95813632);
  float* th     = (float*)(ws + 95817728);

  // 1: weight prep + tmlp1 + ctx->bf16 + silu(LN(x)+pos)   (independent work overlapped)
  prep_all<<<5828, 256, 0, stream>>>(Wq, wt_q, Wkv1, wt_kv1, Wkv2, wt_kv2,
                                     Wm, wt_m, Wff1, wt_ff1, Wff2, wt_ff2,
                                     tin, Wt1, bt1, ub,
                                     ctx, ctx_bf, x, pos, ln_g, ln_b, qin_bf);
  // 2: q-proj (*scale) + kv1 + tmlp2 in ONE full-machine launch
  gemm2_dual<5,1><<<dim3(128, 5), 512, 0, stream>>>(qin_bf, wt_q, bq, q_bf,
                                                    ctx_bf, wt_kv1, bkv1, kv1,
                                                    ub, Wt2, bt2, th,
                                                    256, 256);
  // 3: silu(LN(kv1))
  ln_silu<1><<<2048, 256, 0, stream>>>(kv1, nullptr, kvg, kvb, qin_bf);
  // 4: kv = . @ Wkv2 + bkv2 -> K (bf16) + V transposed directly to VT[bh][d][m]
  gemm2<3><<<dim3(128, 18), 512, 0, stream>>>(qin_bf, wt_kv2, bkv2, nullptr, nullptr,
                                              nullptr, k_bf, vT, 8192, 2304, 256);
  // 5: attention
  attn7<<<dim3(32, 8), 512, 0, stream>>>(q_bf, k_bf, vT, v_bf);
  // 6: x2 = x + att @ Wm + bm  (full-machine gemm3)
  gemm3<<<dim3(256, 2), 256, 0, stream>>>(v_bf, wt_m, bm, x, kv1, 8192, 256, 2048);
  // 7: silu(LN(x2 + t_shift))
  ln_silu<2><<<2048, 256, 0, stream>>>(kv1, th, fg, fb, ctx_bf);
  // 8: h gated FF1 (writes into vT region, reused as gated h)
  gemm2<4><<<dim3(128, 8), 512, 0, stream>>>(ctx_bf, wt_ff1, bff1, nullptr, th,
                                             nullptr, (u16*)vT, nullptr, 8192, 1024, 256);
  // 9: out = h @ Wff2 + bff2 + x2  (full-machine gemm3)
  gemm3<<<dim3(256, 2), 256, 0, stream>>>((u16*)vT, wt_ff2, bff2, kv1,
                                          (float*)d_out, 8192, 256, 1024);
}